// Round 13
// baseline (492.185 us; speedup 1.0000x reference)
//
#include <hip/hip_runtime.h>
#include <hip/hip_bf16.h>
#include <hip/hip_cooperative_groups.h>
#include <math.h>

namespace cg = cooperative_groups;

// ---------------------------------------------------------------------------
// MoNet regression, v11: ONE cooperative mega-kernel, 13 phases / 12
// grid.sync()s, each phase = grid-strided v8 kernel body (129.9us best).
//   * edge_dst = repeat(arange(n),6); hex_pool keeps first L rows;
//     relu commutes with max-pool; gmm_conv folded to node GEMM.
//   * GEMM: mfma_f32_16x16x32_bf16, f32->bf16 hi/lo 3-term split, no LDS,
//     grid-strided (tile,z) split-K partials; pool phase adds bias+relu.
//   * R4 lesson: VGPR cap (256 via launch_bounds(256,2)) >> need (~130).
//   * R7 lesson: all reduction phases stay wide.
//   * R11/R12 lesson: v9's weight-hoist and fc1_head both regressed — v8
//     phase bodies kept verbatim (head1 + fc1_part + head2).
// ---------------------------------------------------------------------------

#define GEPS 1e-15f

typedef __attribute__((ext_vector_type(8))) short short8;
typedef __attribute__((ext_vector_type(4))) float f32x4;

struct MParams {
    const float *x0;
    const int *src6; const float *pseudo6; const int *hex6;
    const int *src5; const float *pseudo5; const int *hex5;
    const int *src4; const float *pseudo4; const int *hex4;
    const int *src3; const float *pseudo3; const int *hex3;
    const float *g1,*mu1,*sg1,*rt1,*b1;
    const float *g2,*mu2,*sg2,*rt2,*b2;
    const float *g3,*mu3,*sg3,*rt3,*b3;
    const float *g4,*mu4,*sg4,*rt4,*b4;
    const float *fcW,*fcb,*fc2W,*fc2b;
    __hip_bfloat16 *Ahi,*Alo,*Bthi,*Btlo;
    float *CG,*pooled,*xc,*fcpart,*out;
};

__device__ inline void sthl(__hip_bfloat16* H, __hip_bfloat16* L, size_t idx, float v)
{
    __hip_bfloat16 h = __float2bfloat16(v);
    H[idx] = h;
    L[idx] = __float2bfloat16(v - __bfloat162float(h));
}

// ---------------- phase: L6 conv + hexpool (cin=4, K=16, cout=64) -----------
__device__ void conv6_phase(const MParams& p, float* sm, int G)
{
    float* Bs  = sm;                  // 16*68 = 1088
    int*   hl  = (int*)(sm + 1088);   // 112
    float* xle = sm + 1200;           // 112*6*4 = 2688
    float* wle = sm + 3888;           // 112*18 = 2016
    float* Als = sm + 5904;           // 112*20 = 2240 (end 8144)
    const int t = threadIdx.x;
    const int L = 10242;

    float muv[9], sgv[9];
#pragma unroll
    for (int q = 0; q < 9; ++q) { muv[q] = p.mu1[q]; sgv[q] = p.sg1[q]; }

    for (int idx = t; idx < 1024; idx += 256) {
        int jj = idx >> 6, o = idx & 63;
        float v;
        if (jj < 12) { int k = jj >> 2, c = jj & 3; v = p.g1[c * 192 + k * 64 + o]; }
        else v = p.rt1[(jj - 12) * 64 + o];
        Bs[jj * 68 + o] = v;
    }
    __syncthreads();
    const int c = t & 63;
    float breg[16];
#pragma unroll
    for (int k = 0; k < 16; ++k) breg[k] = Bs[k * 68 + c];
    const float bv = p.b1[c];

    for (int bid = blockIdx.x; bid < (L + 15) / 16; bid += G) {
        const int i0 = bid * 16;
        if (t < 112) {
            int i = i0 + t / 7;
            hl[t] = (i < L) ? p.hex6[i * 7 + (t - (t / 7) * 7)] : 0;
        }
        __syncthreads();
        for (int e = t; e < 672; e += 256) {
            int f = e / 6, el = e - f * 6;
            int ge = hl[f] * 6 + el;
            float4 xv = *(const float4*)&p.x0[(size_t)p.src6[ge] * 4];
            float q0 = p.pseudo6[ge * 3 + 0], q1 = p.pseudo6[ge * 3 + 1], q2 = p.pseudo6[ge * 3 + 2];
            float w0, w1, w2;
#pragma unroll
            for (int k = 0; k < 3; ++k) {
                float d0 = q0 - muv[k * 3 + 0], d1 = q1 - muv[k * 3 + 1], d2 = q2 - muv[k * 3 + 2];
                float s0 = sgv[k * 3 + 0], s1 = sgv[k * 3 + 1], s2 = sgv[k * 3 + 2];
                float s = d0 * d0 / (s0 * s0 + GEPS) + d1 * d1 / (s1 * s1 + GEPS)
                        + d2 * d2 / (s2 * s2 + GEPS);
                float wv = expf(-0.5f * s);
                if (k == 0) w0 = wv; else if (k == 1) w1 = wv; else w2 = wv;
            }
            *(float4*)&xle[(f * 6 + el) * 4] = xv;
            wle[f * 18 + el * 3 + 0] = w0;
            wle[f * 18 + el * 3 + 1] = w1;
            wle[f * 18 + el * 3 + 2] = w2;
        }
        __syncthreads();
        for (int ent = t; ent < 1344; ent += 256) {
            int f = ent / 12, j = ent - f * 12;
            int k = j >> 2, cc = j & 3;
            float a = 0.f;
#pragma unroll
            for (int e = 0; e < 6; ++e)
                a += wle[f * 18 + e * 3 + k] * xle[(f * 6 + e) * 4 + cc];
            Als[f * 20 + j] = a * (1.f / 6.f);
        }
        for (int ent = t; ent < 448; ent += 256) {
            int f = ent >> 2, d = ent & 3;
            Als[f * 20 + 12 + d] = p.x0[(size_t)hl[f] * 4 + d];
        }
        __syncthreads();
#pragma unroll
        for (int q = 0; q < 4; ++q) {
            int co = (t >> 6) * 4 + q;
            int i = i0 + co;
            if (i < L) {
                float m = -INFINITY;
#pragma unroll
                for (int j = 0; j < 7; ++j) {
                    const float* af = &Als[(co * 7 + j) * 20];
                    float d = af[0]*breg[0] + af[1]*breg[1] + af[2]*breg[2] + af[3]*breg[3]
                            + af[4]*breg[4] + af[5]*breg[5] + af[6]*breg[6] + af[7]*breg[7]
                            + af[8]*breg[8] + af[9]*breg[9] + af[10]*breg[10] + af[11]*breg[11]
                            + af[12]*breg[12] + af[13]*breg[13] + af[14]*breg[14] + af[15]*breg[15];
                    m = fmaxf(m, d);
                }
                p.pooled[(size_t)i * 64 + c] = fmaxf(m + bv, 0.f);
            }
        }
        __syncthreads();
    }
}

// ---------------- phase: build [A|x] bf16 hi/lo + weight transpose ----------
template <int CIN>
__device__ void prep_phase(const float* x, const int* src, const float* pseudo,
                           const float* mu, const float* sigma,
                           const float* g, const float* root,
                           __hip_bfloat16* Ahi, __hip_bfloat16* Alo,
                           __hip_bfloat16* Bthi, __hip_bfloat16* Btlo,
                           int n, int cout, float* sm, int G)
{
    constexpr int KK = 4 * CIN;
    constexpr int K3 = 3 * CIN;
    constexpr int NB = 256 / CIN;
    constexpr int NE = NB * 6;
    float* s_w   = sm;                 // <= 72
    int*   s_src = (int*)(sm + 96);    // <= 24
    float* s_mu  = sm + 128;
    float* s_sig = sm + 140;

    const int tid = threadIdx.x;
    if (tid < 9) { s_mu[tid] = mu[tid]; s_sig[tid] = sigma[tid]; }
    __syncthreads();

    const int nbA = (n + NB - 1) / NB;
    const int nbW = KK * cout / 256;
    const int nE = n * 6;

    for (int b = blockIdx.x; b < nbA + nbW; b += G) {
        if (b >= nbA) {
            // weight transpose/convert: W[j][c] -> Bt[c][j]
            int idx0 = (b - nbA) * 256 + tid;
            int j = idx0 & (KK - 1);
            int c = idx0 / KK;
            float v;
            if (j < K3) {
                int kq = j / CIN, cc = j & (CIN - 1);
                v = g[(size_t)cc * (3 * cout) + (size_t)kq * cout + c];
            } else {
                v = root[(size_t)(j - K3) * cout + c];
            }
            sthl(Bthi, Btlo, (size_t)c * KK + j, v);
            continue;
        }
        const int ebase = b * NE;
        for (int tt = tid; tt < NE; tt += 256) {
            int e = ebase + tt;
            if (e < nE) s_src[tt] = src[e];
        }
        for (int tt = tid; tt < NE * 3; tt += 256) {
            int e_l = tt / 3, k = tt - e_l * 3;
            int e = ebase + e_l;
            if (e < nE) {
                float s = 0.f;
#pragma unroll
                for (int d = 0; d < 3; ++d) {
                    float diff = pseudo[e * 3 + d] - s_mu[k * 3 + d];
                    float sg = s_sig[k * 3 + d];
                    s += diff * diff / (sg * sg + GEPS);
                }
                s_w[tt] = expf(-0.5f * s);
            }
        }
        __syncthreads();
        const int il = tid / CIN;
        const int c  = tid - il * CIN;
        const int i  = b * NB + il;
        if (i < n) {
            float a0 = 0.f, a1 = 0.f, a2 = 0.f;
#pragma unroll
            for (int e = 0; e < 6; ++e) {
                int s = s_src[il * 6 + e];
                float xv = x[(size_t)s * CIN + c];
                const float* wp = &s_w[(il * 6 + e) * 3];
                a0 += wp[0] * xv; a1 += wp[1] * xv; a2 += wp[2] * xv;
            }
            const float inv6 = 1.f / 6.f;
            size_t base = (size_t)i * KK;
            sthl(Ahi, Alo, base + 0 * CIN + c, a0 * inv6);
            sthl(Ahi, Alo, base + 1 * CIN + c, a1 * inv6);
            sthl(Ahi, Alo, base + 2 * CIN + c, a2 * inv6);
            sthl(Ahi, Alo, base + 3 * CIN + c, x[(size_t)i * CIN + c]);
        }
        __syncthreads();
    }
}

// ---------------- phase: MFMA GEMM (tile,z grid-strided) --------------------
__device__ void gemm_phase(const __hip_bfloat16* Ahi, const __hip_bfloat16* Alo,
                           const __hip_bfloat16* Bthi, const __hip_bfloat16* Btlo,
                           float* part, int n, int KK, int cout, int nz, int G)
{
    const int gx = (n + 63) >> 6, gy = cout >> 6;
    const int total = gx * gy * nz;
    const int l  = threadIdx.x & 63;
    const int w  = threadIdx.x >> 6;
    const int wr = w >> 1, wc = w & 1;
    const int KC = KK / nz;

    for (int b = blockIdx.x; b < total; b += G) {
        int bz = b / (gx * gy);
        int rem = b - bz * gx * gy;
        int byy = rem / gx, bxx = rem - byy * gx;
        const int bm = bxx * 64, bn = byy * 64;
        const int kbase = bz * KC + ((l >> 4) << 3);

        int r0 = bm + wr * 32 + (l & 15);
        int r1 = r0 + 16;
        if (r0 >= n) r0 = n - 1;
        if (r1 >= n) r1 = n - 1;
        const int c0 = bn + wc * 32 + (l & 15);
        const int c1 = c0 + 16;

        const __hip_bfloat16* pA0h = Ahi + (size_t)r0 * KK + kbase;
        const __hip_bfloat16* pA0l = Alo + (size_t)r0 * KK + kbase;
        const __hip_bfloat16* pA1h = Ahi + (size_t)r1 * KK + kbase;
        const __hip_bfloat16* pA1l = Alo + (size_t)r1 * KK + kbase;
        const __hip_bfloat16* pB0h = Bthi + (size_t)c0 * KK + kbase;
        const __hip_bfloat16* pB0l = Btlo + (size_t)c0 * KK + kbase;
        const __hip_bfloat16* pB1h = Bthi + (size_t)c1 * KK + kbase;
        const __hip_bfloat16* pB1l = Btlo + (size_t)c1 * KK + kbase;

        f32x4 acc00 = {0.f,0.f,0.f,0.f}, acc01 = acc00, acc10 = acc00, acc11 = acc00;

        const int steps = KC >> 5;
        for (int ks = 0; ks < steps; ++ks) {
            const int ko = ks * 32;
            short8 ah0 = *(const short8*)(pA0h + ko);
            short8 al0 = *(const short8*)(pA0l + ko);
            short8 ah1 = *(const short8*)(pA1h + ko);
            short8 al1 = *(const short8*)(pA1l + ko);
            short8 bh0 = *(const short8*)(pB0h + ko);
            short8 bl0 = *(const short8*)(pB0l + ko);
            short8 bh1 = *(const short8*)(pB1h + ko);
            short8 bl1 = *(const short8*)(pB1l + ko);

            acc00 = __builtin_amdgcn_mfma_f32_16x16x32_bf16(ah0, bh0, acc00, 0, 0, 0);
            acc01 = __builtin_amdgcn_mfma_f32_16x16x32_bf16(ah0, bh1, acc01, 0, 0, 0);
            acc10 = __builtin_amdgcn_mfma_f32_16x16x32_bf16(ah1, bh0, acc10, 0, 0, 0);
            acc11 = __builtin_amdgcn_mfma_f32_16x16x32_bf16(ah1, bh1, acc11, 0, 0, 0);
            acc00 = __builtin_amdgcn_mfma_f32_16x16x32_bf16(ah0, bl0, acc00, 0, 0, 0);
            acc01 = __builtin_amdgcn_mfma_f32_16x16x32_bf16(ah0, bl1, acc01, 0, 0, 0);
            acc10 = __builtin_amdgcn_mfma_f32_16x16x32_bf16(ah1, bl0, acc10, 0, 0, 0);
            acc11 = __builtin_amdgcn_mfma_f32_16x16x32_bf16(ah1, bl1, acc11, 0, 0, 0);
            acc00 = __builtin_amdgcn_mfma_f32_16x16x32_bf16(al0, bh0, acc00, 0, 0, 0);
            acc01 = __builtin_amdgcn_mfma_f32_16x16x32_bf16(al0, bh1, acc01, 0, 0, 0);
            acc10 = __builtin_amdgcn_mfma_f32_16x16x32_bf16(al1, bh0, acc10, 0, 0, 0);
            acc11 = __builtin_amdgcn_mfma_f32_16x16x32_bf16(al1, bh1, acc11, 0, 0, 0);
        }

        // C/D layout: col = lane&15, row = (lane>>4)*4 + reg  [m89-verified]
        float* po = part + (size_t)bz * n * cout;
        const int rb = (l >> 4) << 2;
#define ST_TILE(accv, SR, SC)                                                 \
        {                                                                     \
            int rr = bm + wr * 32 + (SR) * 16 + rb;                           \
            int cc = bn + wc * 32 + (SC) * 16 + (l & 15);                     \
            _Pragma("unroll")                                                 \
            for (int q = 0; q < 4; ++q)                                       \
                if (rr + q < n) po[(size_t)(rr + q) * cout + cc] = accv[q];   \
        }
        ST_TILE(acc00, 0, 0); ST_TILE(acc01, 0, 1);
        ST_TILE(acc10, 1, 0); ST_TILE(acc11, 1, 1);
#undef ST_TILE
    }
}

// ---------------- phase: z-reduce + bias + relu + hexpool -------------------
__device__ void pool_phase(const float* part, const int* hx, const float* bias,
                           float* outp, int L, int C, int n, int nz, int G)
{
    int C4 = C >> 2;
    int total = L * C4;
    for (int idx = blockIdx.x * 256 + threadIdx.x; idx < total; idx += G * 256) {
        int i = idx / C4, c4 = (idx - i * C4) * 4;
        const int* h = &hx[i * 7];
        float4 bv = *(const float4*)&bias[c4];
        size_t stride = (size_t)n * C;
        float4 m = make_float4(-INFINITY, -INFINITY, -INFINITY, -INFINITY);
#pragma unroll 7
        for (int j = 0; j < 7; ++j) {
            const float* pr = &part[(size_t)h[j] * C + c4];
            float4 s = bv;
            for (int z = 0; z < nz; ++z) {
                float4 pv = *(const float4*)&pr[z * stride];
                s.x += pv.x; s.y += pv.y; s.z += pv.z; s.w += pv.w;
            }
            m.x = fmaxf(m.x, s.x); m.y = fmaxf(m.y, s.y);
            m.z = fmaxf(m.z, s.z); m.w = fmaxf(m.w, s.w);
        }
        m.x = fmaxf(m.x, 0.f); m.y = fmaxf(m.y, 0.f);
        m.z = fmaxf(m.z, 0.f); m.w = fmaxf(m.w, 0.f);
        *(float4*)&outp[(size_t)i * C + c4] = m;
    }
}

// ---------------- phases: head ----------------------------------------------
__device__ void head1_phase(const MParams& p, float* sm, int G)
{
    float* s_mx = sm;        // 4*64
    float* s_sm = sm + 256;  // 4*64
    const int t = threadIdx.x;
    for (int b = blockIdx.x; b < 8; b += G) {
        const int c = b * 64 + (t & 63);
        const int rg = t >> 6;
        float mx = -INFINITY, sum = 0.f;
        for (int r = rg; r < 162; r += 4) {
            float v = p.pooled[r * 512 + c];
            mx = fmaxf(mx, v);
            sum += v;
        }
        s_mx[rg * 64 + (t & 63)] = mx;
        s_sm[rg * 64 + (t & 63)] = sum;
        __syncthreads();
        if (rg == 0) {
#pragma unroll
            for (int q = 1; q < 4; ++q) {
                mx = fmaxf(mx, s_mx[q * 64 + t]);
                sum += s_sm[q * 64 + t];
            }
            p.xc[c] = mx;
            p.xc[512 + c] = sum * (1.f / 162.f);
        }
        __syncthreads();
    }
}

__device__ void fc1_phase(const MParams& p, float* sm, int G)
{
    float* s_p = sm;   // 4*64
    const int t = threadIdx.x;
    for (int b = blockIdx.x; b < 64; b += G) {
        const int ox = b & 7, jy = b >> 3;
        const int o = ox * 64 + (t & 63);
        const int jg = t >> 6;
        const int jbase = jy * 128 + jg * 32;
        float acc = 0.f;
#pragma unroll
        for (int jj = 0; jj < 32; ++jj)
            acc += p.xc[jbase + jj] * p.fcW[(size_t)(jbase + jj) * 512 + o];
        s_p[jg * 64 + (t & 63)] = acc;
        __syncthreads();
        if (jg == 0) {
#pragma unroll
            for (int q = 1; q < 4; ++q) acc += s_p[q * 64 + t];
            p.fcpart[jy * 512 + o] = acc;
        }
        __syncthreads();
    }
}

__device__ void head2_phase(const MParams& p, float* sm)
{
    if (blockIdx.x != 0) return;
    float* red = sm;  // 256
    const int t = threadIdx.x;
    float p0 = p.fcb[t], p1 = p.fcb[t + 256];
#pragma unroll
    for (int q = 0; q < 8; ++q) {
        p0 += p.fcpart[q * 512 + t];
        p1 += p.fcpart[q * 512 + t + 256];
    }
    red[t] = fmaxf(p0, 0.f) * p.fc2W[t] + fmaxf(p1, 0.f) * p.fc2W[t + 256];
    __syncthreads();
    for (int s = 128; s > 0; s >>= 1) {
        if (t < s) red[t] += red[t + s];
        __syncthreads();
    }
    if (t == 0) p.out[0] = red[0] + p.fc2b[0];
}

// ---------------- the mega-kernel -------------------------------------------
__global__ __launch_bounds__(256, 2) void monet_mega(MParams p)
{
    __shared__ float sm[8160];
    cg::grid_group gg = cg::this_grid();
    const int G = gridDim.x;

    conv6_phase(p, sm, G);                                           gg.sync();
    prep_phase<64>(p.pooled, p.src5, p.pseudo5, p.mu2, p.sg2, p.g2, p.rt2,
                   p.Ahi, p.Alo, p.Bthi, p.Btlo, 10242, 128, sm, G); gg.sync();
    gemm_phase(p.Ahi, p.Alo, p.Bthi, p.Btlo, p.CG, 10242, 256, 128, 2, G); gg.sync();
    pool_phase(p.CG, p.hex5, p.b2, p.pooled, 2562, 128, 10242, 2, G); gg.sync();

    prep_phase<128>(p.pooled, p.src4, p.pseudo4, p.mu3, p.sg3, p.g3, p.rt3,
                    p.Ahi, p.Alo, p.Bthi, p.Btlo, 2562, 256, sm, G); gg.sync();
    gemm_phase(p.Ahi, p.Alo, p.Bthi, p.Btlo, p.CG, 2562, 512, 256, 2, G); gg.sync();
    pool_phase(p.CG, p.hex4, p.b3, p.pooled, 642, 256, 2562, 2, G);  gg.sync();

    prep_phase<256>(p.pooled, p.src3, p.pseudo3, p.mu4, p.sg4, p.g4, p.rt4,
                    p.Ahi, p.Alo, p.Bthi, p.Btlo, 642, 512, sm, G);  gg.sync();
    gemm_phase(p.Ahi, p.Alo, p.Bthi, p.Btlo, p.CG, 642, 1024, 512, 4, G); gg.sync();
    pool_phase(p.CG, p.hex3, p.b4, p.pooled, 162, 512, 642, 4, G);   gg.sync();

    head1_phase(p, sm, G);                                           gg.sync();
    fc1_phase(p, sm, G);                                             gg.sync();
    head2_phase(p, sm);
}

// ---------------------------------------------------------------------------
extern "C" void kernel_launch(void* const* d_in, const int* in_sizes, int n_in,
                              void* d_out, int out_size, void* d_ws, size_t ws_size,
                              hipStream_t stream)
{
    MParams p;
    p.x0      = (const float*)d_in[0];
    p.src6    = (const int*)  d_in[1];
    p.pseudo6 = (const float*)d_in[3];
    p.hex6    = (const int*)  d_in[4];
    p.src5    = (const int*)  d_in[5];
    p.pseudo5 = (const float*)d_in[7];
    p.hex5    = (const int*)  d_in[8];
    p.src4    = (const int*)  d_in[9];
    p.pseudo4 = (const float*)d_in[11];
    p.hex4    = (const int*)  d_in[12];
    p.src3    = (const int*)  d_in[13];
    p.pseudo3 = (const float*)d_in[15];
    p.hex3    = (const int*)  d_in[16];
    p.g1 = (const float*)d_in[17]; p.mu1 = (const float*)d_in[18];
    p.sg1 = (const float*)d_in[19]; p.rt1 = (const float*)d_in[20];
    p.b1 = (const float*)d_in[21];
    p.g2 = (const float*)d_in[22]; p.mu2 = (const float*)d_in[23];
    p.sg2 = (const float*)d_in[24]; p.rt2 = (const float*)d_in[25];
    p.b2 = (const float*)d_in[26];
    p.g3 = (const float*)d_in[27]; p.mu3 = (const float*)d_in[28];
    p.sg3 = (const float*)d_in[29]; p.rt3 = (const float*)d_in[30];
    p.b3 = (const float*)d_in[31];
    p.g4 = (const float*)d_in[32]; p.mu4 = (const float*)d_in[33];
    p.sg4 = (const float*)d_in[34]; p.rt4 = (const float*)d_in[35];
    p.b4 = (const float*)d_in[36];
    p.fcW = (const float*)d_in[37]; p.fcb = (const float*)d_in[38];
    p.fc2W = (const float*)d_in[39]; p.fc2b = (const float*)d_in[40];

    const size_t MB = 1u << 20;
    char* wb = (char*)d_ws;
    p.Ahi    = (__hip_bfloat16*)(wb + 0 * MB);   // <= 5.25 MB
    p.Alo    = (__hip_bfloat16*)(wb + 6 * MB);   // <= 5.25 MB
    p.Bthi   = (__hip_bfloat16*)(wb + 12 * MB);  // <= 1 MB
    p.Btlo   = (__hip_bfloat16*)(wb + 14 * MB);  // <= 1 MB
    p.CG     = (float*)(wb + 16 * MB);           // z-partials, <= 10.5 MB
    p.pooled = (float*)(wb + 28 * MB);           // <= 2.62 MB
    p.xc     = (float*)(wb + 31 * MB);           // 4 KB
    p.fcpart = (float*)(wb + 31 * MB + 16384);   // 16 KB
    p.out    = (float*)d_out;

    // co-residency: LDS 32.6KB -> >=2 blocks/CU; launch_bounds(256,2) caps
    // VGPR at 256 so 512 blocks are guaranteed co-resident; verify anyway.
    int mb = 0;
    hipOccupancyMaxActiveBlocksPerMultiprocessor(&mb, monet_mega, 256, 0);
    if (mb < 1) mb = 1;
    int nblk = 256 * (mb < 2 ? mb : 2);

    void* args[] = { &p };
    hipLaunchCooperativeKernel((void*)monet_mega, dim3(nblk), dim3(256),
                               args, 0, stream);
}

// Round 14
// 130.162 us; speedup vs baseline: 3.7813x; 3.7813x over previous
//
#include <hip/hip_runtime.h>
#include <hip/hip_bf16.h>
#include <math.h>

// ---------------------------------------------------------------------------
// MoNet regression on icosphere graphs.  v8 (R10 best, 129.9us) — reverted
// after three structural experiments regressed:
//   R11: weight-transpose hoist into conv6pool (+7us — uncoalesced g-reads
//        extended dispatch 1 past the conv shadow)
//   R12: head1->fc1 fusion (+8us)
//   R13: cooperative mega-kernel (492us — phase-union VGPR spill @68 regs,
//        LDS-union occupancy cap, 12 grid.syncs costlier than launch gaps)
// Structure:
//   * edge_dst = repeat(arange(n), 6) -> node i owns edges [6i,6i+6)
//   * gmm_conv folded:  A[i,k*cin+c] = (1/6) sum_e w[e,k] x[src[e],c]
//       out = relu([A|x] @ [G'|root] + b)
//   * L6: conv+hexpool fused (conv6pool), 641 wide blocks.
//   * L5/L4/L3: prep (build_A bf16 hi/lo + weight transpose, one dispatch)
//     -> gemm_mfma (16x16x32 bf16, 3-term hi/lo split, no LDS, ~110 VGPR)
//     with grid.z split-K -> fused z-reduce+bias+relu+hexpool.
//   * head: head1 (8 blocks) + fc1_part (64 blocks) + head2.  13 dispatches.
//   * R4 lesson: no VGPR-capping launch_bounds on the MFMA kernel.
//   * R7 lesson: keep reduction tails wide (no 8-block serial gathers).
// ---------------------------------------------------------------------------

#define GEPS 1e-15f

typedef __attribute__((ext_vector_type(8))) short short8;
typedef __attribute__((ext_vector_type(4))) float f32x4;

__device__ inline void sthl(__hip_bfloat16* H, __hip_bfloat16* L, size_t idx, float v)
{
    __hip_bfloat16 h = __float2bfloat16(v);
    H[idx] = h;
    L[idx] = __float2bfloat16(v - __bfloat162float(h));
}

// ---------------- prep: build [A|x] bf16 hi/lo  +  weight transpose ---------
template <int CIN>
__global__ __launch_bounds__(256) void prep_kern(
    const float* __restrict__ x,      // (n_src, CIN)
    const int*   __restrict__ src,    // (6n)
    const float* __restrict__ pseudo, // (6n, 3)
    const float* __restrict__ mu,     // (3,3)
    const float* __restrict__ sigma,  // (3,3)
    const float* __restrict__ g,      // (CIN, 3*cout)
    const float* __restrict__ root,   // (CIN, cout)
    __hip_bfloat16* __restrict__ Ahi, // (n, KK)
    __hip_bfloat16* __restrict__ Alo,
    __hip_bfloat16* __restrict__ Bthi,// (cout, KK)
    __hip_bfloat16* __restrict__ Btlo,
    int n, int cout, int nbA)
{
    constexpr int KK = 4 * CIN;
    constexpr int K3 = 3 * CIN;

    if ((int)blockIdx.x >= nbA) {
        int idx0 = (blockIdx.x - nbA) * 256 + threadIdx.x;   // < KK*cout
        int j = idx0 & (KK - 1);
        int c = idx0 / KK;
        float v;
        if (j < K3) {
            int kq = j / CIN, cc = j & (CIN - 1);
            v = g[(size_t)cc * (3 * cout) + (size_t)kq * cout + c];
        } else {
            v = root[(size_t)(j - K3) * cout + c];
        }
        sthl(Bthi, Btlo, (size_t)c * KK + j, v);
        return;
    }

    constexpr int NB = 256 / CIN;
    constexpr int NE = NB * 6;
    __shared__ float s_w[NE * 3];
    __shared__ int   s_src[NE];
    __shared__ float s_mu[9], s_sig[9];

    const int tid = threadIdx.x;
    if (tid < 9) { s_mu[tid] = mu[tid]; s_sig[tid] = sigma[tid]; }
    __syncthreads();

    const int ebase = blockIdx.x * NE;
    const int nE = n * 6;
    for (int t = tid; t < NE; t += 256) {
        int e = ebase + t;
        if (e < nE) s_src[t] = src[e];
    }
    for (int t = tid; t < NE * 3; t += 256) {
        int e_l = t / 3, k = t - e_l * 3;
        int e = ebase + e_l;
        if (e < nE) {
            float s = 0.f;
#pragma unroll
            for (int d = 0; d < 3; ++d) {
                float diff = pseudo[e * 3 + d] - s_mu[k * 3 + d];
                float sg = s_sig[k * 3 + d];
                s += diff * diff / (sg * sg + GEPS);
            }
            s_w[t] = expf(-0.5f * s);
        }
    }
    __syncthreads();

    const int il = tid / CIN;
    const int c  = tid - il * CIN;
    const int i  = blockIdx.x * NB + il;
    if (i < n) {
        float a0 = 0.f, a1 = 0.f, a2 = 0.f;
#pragma unroll
        for (int e = 0; e < 6; ++e) {
            int s = s_src[il * 6 + e];
            float xv = x[(size_t)s * CIN + c];
            const float* wp = &s_w[(il * 6 + e) * 3];
            a0 += wp[0] * xv; a1 += wp[1] * xv; a2 += wp[2] * xv;
        }
        const float inv6 = 1.f / 6.f;
        size_t base = (size_t)i * KK;
        sthl(Ahi, Alo, base + 0 * CIN + c, a0 * inv6);
        sthl(Ahi, Alo, base + 1 * CIN + c, a1 * inv6);
        sthl(Ahi, Alo, base + 2 * CIN + c, a2 * inv6);
        sthl(Ahi, Alo, base + 3 * CIN + c, x[(size_t)i * CIN + c]);
    }
}

// ---------------- MFMA GEMM: 64x64 tile, 4 waves x (32x32), split-K z -------
__global__ __launch_bounds__(256) void gemm_mfma(
    const __hip_bfloat16* __restrict__ Ahi,  // (n, KK)
    const __hip_bfloat16* __restrict__ Alo,
    const __hip_bfloat16* __restrict__ Bthi, // (cout, KK)
    const __hip_bfloat16* __restrict__ Btlo,
    float* __restrict__ part,                // (nz, n, cout) raw partials
    int n, int KK, int cout)
{
    const int l  = threadIdx.x & 63;
    const int w  = threadIdx.x >> 6;       // 0..3
    const int wr = w >> 1, wc = w & 1;
    const int bm = blockIdx.x * 64;
    const int bn = blockIdx.y * 64;
    const int KC = KK / gridDim.z;
    const int kbase = blockIdx.z * KC + ((l >> 4) << 3);

    int r0 = bm + wr * 32 + (l & 15);
    int r1 = r0 + 16;
    if (r0 >= n) r0 = n - 1;
    if (r1 >= n) r1 = n - 1;
    const int c0 = bn + wc * 32 + (l & 15);
    const int c1 = c0 + 16;

    const __hip_bfloat16* pA0h = Ahi + (size_t)r0 * KK + kbase;
    const __hip_bfloat16* pA0l = Alo + (size_t)r0 * KK + kbase;
    const __hip_bfloat16* pA1h = Ahi + (size_t)r1 * KK + kbase;
    const __hip_bfloat16* pA1l = Alo + (size_t)r1 * KK + kbase;
    const __hip_bfloat16* pB0h = Bthi + (size_t)c0 * KK + kbase;
    const __hip_bfloat16* pB0l = Btlo + (size_t)c0 * KK + kbase;
    const __hip_bfloat16* pB1h = Bthi + (size_t)c1 * KK + kbase;
    const __hip_bfloat16* pB1l = Btlo + (size_t)c1 * KK + kbase;

    f32x4 acc00 = {0.f, 0.f, 0.f, 0.f}, acc01 = acc00, acc10 = acc00, acc11 = acc00;

    const int steps = KC >> 5;
    for (int ks = 0; ks < steps; ++ks) {
        const int ko = ks * 32;
        short8 ah0 = *(const short8*)(pA0h + ko);
        short8 al0 = *(const short8*)(pA0l + ko);
        short8 ah1 = *(const short8*)(pA1h + ko);
        short8 al1 = *(const short8*)(pA1l + ko);
        short8 bh0 = *(const short8*)(pB0h + ko);
        short8 bl0 = *(const short8*)(pB0l + ko);
        short8 bh1 = *(const short8*)(pB1h + ko);
        short8 bl1 = *(const short8*)(pB1l + ko);

        acc00 = __builtin_amdgcn_mfma_f32_16x16x32_bf16(ah0, bh0, acc00, 0, 0, 0);
        acc01 = __builtin_amdgcn_mfma_f32_16x16x32_bf16(ah0, bh1, acc01, 0, 0, 0);
        acc10 = __builtin_amdgcn_mfma_f32_16x16x32_bf16(ah1, bh0, acc10, 0, 0, 0);
        acc11 = __builtin_amdgcn_mfma_f32_16x16x32_bf16(ah1, bh1, acc11, 0, 0, 0);
        acc00 = __builtin_amdgcn_mfma_f32_16x16x32_bf16(ah0, bl0, acc00, 0, 0, 0);
        acc01 = __builtin_amdgcn_mfma_f32_16x16x32_bf16(ah0, bl1, acc01, 0, 0, 0);
        acc10 = __builtin_amdgcn_mfma_f32_16x16x32_bf16(ah1, bl0, acc10, 0, 0, 0);
        acc11 = __builtin_amdgcn_mfma_f32_16x16x32_bf16(ah1, bl1, acc11, 0, 0, 0);
        acc00 = __builtin_amdgcn_mfma_f32_16x16x32_bf16(al0, bh0, acc00, 0, 0, 0);
        acc01 = __builtin_amdgcn_mfma_f32_16x16x32_bf16(al0, bh1, acc01, 0, 0, 0);
        acc10 = __builtin_amdgcn_mfma_f32_16x16x32_bf16(al1, bh0, acc10, 0, 0, 0);
        acc11 = __builtin_amdgcn_mfma_f32_16x16x32_bf16(al1, bh1, acc11, 0, 0, 0);
    }

    // C/D layout: col = lane&15, row = (lane>>4)*4 + reg  [m89-verified]
    float* po = part + (size_t)blockIdx.z * n * cout;
    const int rb = (l >> 4) << 2;
#define ST_TILE(accv, SR, SC)                                                 \
    {                                                                         \
        int rr = bm + wr * 32 + (SR) * 16 + rb;                               \
        int cc = bn + wc * 32 + (SC) * 16 + (l & 15);                         \
        _Pragma("unroll")                                                     \
        for (int q = 0; q < 4; ++q)                                           \
            if (rr + q < n) po[(size_t)(rr + q) * cout + cc] = accv[q];       \
    }
    ST_TILE(acc00, 0, 0); ST_TILE(acc01, 0, 1);
    ST_TILE(acc10, 1, 0); ST_TILE(acc11, 1, 1);
#undef ST_TILE
}

// ---------------- fused L6 conv + hexpool (cin=4, K=16, cout=64) ------------
#define NCO 16
__global__ __launch_bounds__(256) void conv6pool(
    const float* __restrict__ x,      // (n,4)
    const int*   __restrict__ src,    // (6n)
    const float* __restrict__ pseudo, // (6n,3)
    const float* __restrict__ mu,     // (3,3)
    const float* __restrict__ sigma,  // (3,3)
    const float* __restrict__ g,      // (4,192)
    const float* __restrict__ root,   // (4,64)
    const float* __restrict__ bias,   // (64)
    const int*   __restrict__ hx,     // (n,7), first L rows used
    float* __restrict__ pooled,       // (L,64)
    int n, int L)
{
    __shared__ float Bs[16][68];
    __shared__ int   hlist[NCO * 7];
    __shared__ float xle[NCO * 7][6][4];
    __shared__ float wle[NCO * 7][18];
    __shared__ float Als[NCO * 7][20];

    const int t = threadIdx.x;
    const int i0 = blockIdx.x * NCO;

    float muv[9], sgv[9];
#pragma unroll
    for (int q = 0; q < 9; ++q) { muv[q] = mu[q]; sgv[q] = sigma[q]; }

    for (int idx = t; idx < 1024; idx += 256) {
        int jj = idx >> 6, o = idx & 63;
        float v;
        if (jj < 12) { int k = jj >> 2, c = jj & 3; v = g[c * 192 + k * 64 + o]; }
        else v = root[(jj - 12) * 64 + o];
        Bs[jj][o] = v;
    }
    if (t < NCO * 7) {
        int i = i0 + t / 7;
        hlist[t] = (i < L) ? hx[i * 7 + (t - (t / 7) * 7)] : 0;
    }
    __syncthreads();

    for (int e = t; e < NCO * 7 * 6; e += 256) {
        int f = e / 6, el = e - f * 6;
        int ge = hlist[f] * 6 + el;
        float4 xv = *(const float4*)&x[(size_t)src[ge] * 4];
        float p0 = pseudo[ge * 3 + 0], p1 = pseudo[ge * 3 + 1], p2 = pseudo[ge * 3 + 2];
        float w0, w1, w2;
#pragma unroll
        for (int k = 0; k < 3; ++k) {
            float d0 = p0 - muv[k * 3 + 0], d1 = p1 - muv[k * 3 + 1], d2 = p2 - muv[k * 3 + 2];
            float s0 = sgv[k * 3 + 0], s1 = sgv[k * 3 + 1], s2 = sgv[k * 3 + 2];
            float s = d0 * d0 / (s0 * s0 + GEPS) + d1 * d1 / (s1 * s1 + GEPS)
                    + d2 * d2 / (s2 * s2 + GEPS);
            float wv = expf(-0.5f * s);
            if (k == 0) w0 = wv; else if (k == 1) w1 = wv; else w2 = wv;
        }
        *(float4*)&xle[f][el][0] = xv;
        wle[f][el * 3 + 0] = w0; wle[f][el * 3 + 1] = w1; wle[f][el * 3 + 2] = w2;
    }
    __syncthreads();

    for (int ent = t; ent < NCO * 7 * 12; ent += 256) {
        int f = ent / 12, j = ent - f * 12;
        int k = j >> 2, c = j & 3;
        float a = 0.f;
#pragma unroll
        for (int e = 0; e < 6; ++e)
            a += wle[f][e * 3 + k] * xle[f][e][c];
        Als[f][j] = a * (1.f / 6.f);
    }
    for (int ent = t; ent < NCO * 7 * 4; ent += 256) {
        int f = ent >> 2, d = ent & 3;
        Als[f][12 + d] = x[(size_t)hlist[f] * 4 + d];
    }
    __syncthreads();

    {
        const int c = t & 63;
        float breg[16];
#pragma unroll
        for (int k = 0; k < 16; ++k) breg[k] = Bs[k][c];
        const float bv = bias[c];
#pragma unroll
        for (int q = 0; q < 4; ++q) {
            int co = (t >> 6) * 4 + q;
            int i = i0 + co;
            if (i < L) {
                float m = -INFINITY;
#pragma unroll
                for (int j = 0; j < 7; ++j) {
                    const float* af = &Als[co * 7 + j][0];
                    float4 a0 = *(const float4*)&af[0];
                    float4 a1 = *(const float4*)&af[4];
                    float4 a2 = *(const float4*)&af[8];
                    float4 a3 = *(const float4*)&af[12];
                    float d = a0.x * breg[0] + a0.y * breg[1] + a0.z * breg[2] + a0.w * breg[3]
                            + a1.x * breg[4] + a1.y * breg[5] + a1.z * breg[6] + a1.w * breg[7]
                            + a2.x * breg[8] + a2.y * breg[9] + a2.z * breg[10] + a2.w * breg[11]
                            + a3.x * breg[12] + a3.y * breg[13] + a3.z * breg[14] + a3.w * breg[15];
                    m = fmaxf(m, d);
                }
                pooled[(size_t)i * 64 + c] = fmaxf(m + bv, 0.f);
            }
        }
    }
}

// ---------------- fused z-reduce + bias + relu + hexpool --------------------
__global__ void hexpool_reduce_kern(
    const float* __restrict__ part,  // (nz, n, C)
    const int*   __restrict__ hx,    // (n,7) — first L rows used
    const float* __restrict__ bias,  // (C)
    float* __restrict__ out,         // (L, C)
    int L, int C, int n, int nz)
{
    int idx = blockIdx.x * blockDim.x + threadIdx.x;
    int C4 = C >> 2;
    int total = L * C4;
    if (idx >= total) return;
    int i = idx / C4, c4 = (idx - i * C4) * 4;
    const int* h = &hx[i * 7];
    float4 bv = *(const float4*)&bias[c4];
    size_t stride = (size_t)n * C;
    float4 m = make_float4(-INFINITY, -INFINITY, -INFINITY, -INFINITY);
#pragma unroll 7
    for (int j = 0; j < 7; ++j) {
        const float* pr = &part[(size_t)h[j] * C + c4];
        float4 s = bv;
        for (int z = 0; z < nz; ++z) {
            float4 p = *(const float4*)&pr[z * stride];
            s.x += p.x; s.y += p.y; s.z += p.z; s.w += p.w;
        }
        m.x = fmaxf(m.x, s.x); m.y = fmaxf(m.y, s.y);
        m.z = fmaxf(m.z, s.z); m.w = fmaxf(m.w, s.w);
    }
    m.x = fmaxf(m.x, 0.f); m.y = fmaxf(m.y, 0.f);
    m.z = fmaxf(m.z, 0.f); m.w = fmaxf(m.w, 0.f);
    *(float4*)&out[(size_t)i * C + c4] = m;
}

// ---------------- head ------------------------------------------------------
__global__ __launch_bounds__(256) void head1_kern(const float* __restrict__ xin, // (162,512)
                                                  float* __restrict__ xc)        // (1024)
{
    __shared__ float s_mx[4][64], s_sm[4][64];
    const int t = threadIdx.x;
    const int c = blockIdx.x * 64 + (t & 63);
    const int rg = t >> 6;
    float mx = -INFINITY, sm = 0.f;
    for (int r = rg; r < 162; r += 4) {
        float v = xin[r * 512 + c];
        mx = fmaxf(mx, v);
        sm += v;
    }
    s_mx[rg][t & 63] = mx; s_sm[rg][t & 63] = sm;
    __syncthreads();
    if (rg == 0) {
#pragma unroll
        for (int q = 1; q < 4; ++q) {
            mx = fmaxf(mx, s_mx[q][t]);
            sm += s_sm[q][t];
        }
        xc[c] = mx;
        xc[512 + c] = sm * (1.f / 162.f);
    }
}

__global__ __launch_bounds__(256) void fc1_part_kern(
    const float* __restrict__ xc, const float* __restrict__ fcW,
    float* __restrict__ partials)
{
    __shared__ float s_p[4][64];
    const int t = threadIdx.x;
    const int o = blockIdx.x * 64 + (t & 63);
    const int jg = t >> 6;
    const int jbase = blockIdx.y * 128 + jg * 32;
    float acc = 0.f;
#pragma unroll
    for (int jj = 0; jj < 32; ++jj) {
        int j = jbase + jj;
        acc += xc[j] * fcW[j * 512 + o];
    }
    s_p[jg][t & 63] = acc;
    __syncthreads();
    if (jg == 0) {
#pragma unroll
        for (int q = 1; q < 4; ++q) acc += s_p[q][t];
        partials[blockIdx.y * 512 + o] = acc;
    }
}

__global__ __launch_bounds__(512) void head2_kern(
    const float* __restrict__ partials, const float* __restrict__ fcb,
    const float* __restrict__ fc2W, const float* __restrict__ fc2b,
    float* __restrict__ out)
{
    __shared__ float red[512];
    const int t = threadIdx.x;
    float p = fcb[t];
#pragma unroll
    for (int q = 0; q < 8; ++q) p += partials[q * 512 + t];
    red[t] = fmaxf(p, 0.f) * fc2W[t];
    __syncthreads();
    for (int s = 256; s > 0; s >>= 1) {
        if (t < s) red[t] += red[t + s];
        __syncthreads();
    }
    if (t == 0) out[0] = red[0] + fc2b[0];
}

// ---------------------------------------------------------------------------
extern "C" void kernel_launch(void* const* d_in, const int* in_sizes, int n_in,
                              void* d_out, int out_size, void* d_ws, size_t ws_size,
                              hipStream_t stream)
{
    const float* x0      = (const float*)d_in[0];
    const int*   src6    = (const int*)  d_in[1];
    const float* pseudo6 = (const float*)d_in[3];
    const int*   hex6    = (const int*)  d_in[4];
    const int*   src5    = (const int*)  d_in[5];
    const float* pseudo5 = (const float*)d_in[7];
    const int*   hex5    = (const int*)  d_in[8];
    const int*   src4    = (const int*)  d_in[9];
    const float* pseudo4 = (const float*)d_in[11];
    const int*   hex4    = (const int*)  d_in[12];
    const int*   src3    = (const int*)  d_in[13];
    const float* pseudo3 = (const float*)d_in[15];
    const int*   hex3    = (const int*)  d_in[16];

    const float* g1 = (const float*)d_in[17]; const float* mu1 = (const float*)d_in[18];
    const float* sg1 = (const float*)d_in[19]; const float* rt1 = (const float*)d_in[20];
    const float* b1 = (const float*)d_in[21];
    const float* g2 = (const float*)d_in[22]; const float* mu2 = (const float*)d_in[23];
    const float* sg2 = (const float*)d_in[24]; const float* rt2 = (const float*)d_in[25];
    const float* b2 = (const float*)d_in[26];
    const float* g3 = (const float*)d_in[27]; const float* mu3 = (const float*)d_in[28];
    const float* sg3 = (const float*)d_in[29]; const float* rt3 = (const float*)d_in[30];
    const float* b3 = (const float*)d_in[31];
    const float* g4 = (const float*)d_in[32]; const float* mu4 = (const float*)d_in[33];
    const float* sg4 = (const float*)d_in[34]; const float* rt4 = (const float*)d_in[35];
    const float* b4 = (const float*)d_in[36];
    const float* fcW = (const float*)d_in[37]; const float* fcb = (const float*)d_in[38];
    const float* fc2W = (const float*)d_in[39]; const float* fc2b = (const float*)d_in[40];

    float* out = (float*)d_out;

    const size_t MB = 1u << 20;
    char* wb = (char*)d_ws;
    __hip_bfloat16* Ahi  = (__hip_bfloat16*)(wb + 0 * MB);   // <= 5.25 MB
    __hip_bfloat16* Alo  = (__hip_bfloat16*)(wb + 6 * MB);   // <= 5.25 MB
    __hip_bfloat16* Bthi = (__hip_bfloat16*)(wb + 12 * MB);  // <= 1 MB
    __hip_bfloat16* Btlo = (__hip_bfloat16*)(wb + 14 * MB);  // <= 1 MB
    float* CG     = (float*)(wb + 16 * MB);                  // z-partials, <= 10.5 MB
    float* pooled = (float*)(wb + 28 * MB);                  // <= 2.62 MB
    float* xc     = (float*)(wb + 31 * MB);                  // 1024
    float* fcpart = (float*)(wb + 31 * MB + 8192);           // 8*512

    // ---- level 6: n=40962, cin=4, cout=64 — fused conv+pool ----
    {
        const int n = 40962, L = 10242;
        conv6pool<<<(L + NCO - 1) / NCO, 256, 0, stream>>>(
            x0, src6, pseudo6, mu1, sg1, g1, rt1, b1, hex6, pooled, n, L);
    }
    // ---- level 5: n=10242, cin=64, cout=128 — MFMA, z=2 ----
    {
        const int n = 10242, cout = 128, KK = 256;
        int nbA = (n + 3) / 4, nbW = KK * cout / 256;
        prep_kern<64><<<nbA + nbW, 256, 0, stream>>>(
            pooled, src5, pseudo5, mu2, sg2, g2, rt2, Ahi, Alo, Bthi, Btlo, n, cout, nbA);
        dim3 grid((n + 63) / 64, cout / 64, 2);
        gemm_mfma<<<grid, 256, 0, stream>>>(Ahi, Alo, Bthi, Btlo, CG, n, KK, cout);
        int L = 2562, tot = L * cout / 4;
        hexpool_reduce_kern<<<(tot + 255) / 256, 256, 0, stream>>>(CG, hex5, b2, pooled, L, cout, n, 2);
    }
    // ---- level 4: n=2562, cin=128, cout=256 — MFMA, z=2 ----
    {
        const int n = 2562, cout = 256, KK = 512;
        int nbA = (n + 1) / 2, nbW = KK * cout / 256;
        prep_kern<128><<<nbA + nbW, 256, 0, stream>>>(
            pooled, src4, pseudo4, mu3, sg3, g3, rt3, Ahi, Alo, Bthi, Btlo, n, cout, nbA);
        dim3 grid((n + 63) / 64, cout / 64, 2);
        gemm_mfma<<<grid, 256, 0, stream>>>(Ahi, Alo, Bthi, Btlo, CG, n, KK, cout);
        int L = 642, tot = L * cout / 4;
        hexpool_reduce_kern<<<(tot + 255) / 256, 256, 0, stream>>>(CG, hex4, b3, pooled, L, cout, n, 2);
    }
    // ---- level 3: n=642, cin=256, cout=512 — MFMA, z=4 ----
    {
        const int n = 642, cout = 512, KK = 1024;
        int nbA = n, nbW = KK * cout / 256;
        prep_kern<256><<<nbA + nbW, 256, 0, stream>>>(
            pooled, src3, pseudo3, mu4, sg4, g4, rt4, Ahi, Alo, Bthi, Btlo, n, cout, nbA);
        dim3 grid((n + 63) / 64, cout / 64, 4);
        gemm_mfma<<<grid, 256, 0, stream>>>(Ahi, Alo, Bthi, Btlo, CG, n, KK, cout);
        int L = 162, tot = L * cout / 4;
        hexpool_reduce_kern<<<(tot + 255) / 256, 256, 0, stream>>>(CG, hex3, b4, pooled, L, cout, n, 4);
    }
    // ---- head ----
    head1_kern<<<8, 256, 0, stream>>>(pooled, xc);
    {
        dim3 grid(8, 8);
        fc1_part_kern<<<grid, 256, 0, stream>>>(xc, fcW, fcpart);
    }
    head2_kern<<<1, 512, 0, stream>>>(fcpart, fcb, fc2W, fc2b, out);
}